// Round 4
// baseline (363.930 us; speedup 1.0000x reference)
//
#include <hip/hip_runtime.h>
#include <hip/hip_bf16.h>
#include <math.h>

#define BB 512
#define DD 128
#define CC 100000

// k_main tiling: 32 batch rows x 1024 classes per block, 4 waves,
// each wave = 32 rows x 256 classes (16 class-tiles of 16), zero LDS/barriers.
#define ROWS_PB 32
#define CLS_PW  256
#define CLS_PB  1024
#define NCHUNK  ((CC + CLS_PB - 1) / CLS_PB)   // 98
#define NROWG   (BB / ROWS_PB)                 // 16

__device__ __constant__ const float COS_M  =  0.87758256189037271612f;  // cos(0.5)
__device__ __constant__ const float SIN_M  =  0.47942553860420300538f;  // sin(0.5)
__device__ __constant__ const float THRESH = -0.87758256189037271612f;  // cos(pi-0.5)
__device__ __constant__ const float MMc    =  0.23971276930210150269f;  // sin(0.5)*0.5
#define SCALE_F 64.0f
#define ALPHA_F 1.2f

typedef __attribute__((ext_vector_type(8))) short short8;
typedef __attribute__((ext_vector_type(4))) float float4v;

__device__ inline float waveReduceSum(float v) {
    #pragma unroll
    for (int off = 32; off > 0; off >>= 1)
        v += __shfl_xor(v, off, 64);
    return v;
}

// --- K1: fused feats-normalize (-> bf16 exb) + per-row a_lb (full fp32) ---
__global__ void k_prep(const float* __restrict__ feats, const float* __restrict__ w,
                       const int* __restrict__ labels,
                       __hip_bfloat16* __restrict__ exb, float* __restrict__ alb) {
    int b = blockIdx.x;
    int lane = threadIdx.x;          // 64 threads, 2 floats each
    int lab = labels[b];
    float2 f = ((const float2*)(feats + b * DD))[lane];
    float2 g = ((const float2*)(w + (size_t)lab * DD))[lane];
    float nf  = waveReduceSum(f.x * f.x + f.y * f.y);
    float dot = waveReduceSum(f.x * g.x + f.y * g.y);
    float nw  = waveReduceSum(g.x * g.x + g.y * g.y);
    float rn = rsqrtf(nf);
    __hip_bfloat162 o;
    o.x = __float2bfloat16(f.x * rn);
    o.y = __float2bfloat16(f.y * rn);
    ((__hip_bfloat162*)(exb + b * DD))[lane] = o;
    if (lane == 0) {
        float c = dot * rsqrtf(nf * nw);
        float a;
        if (c > THRESH) {
            float cc = fminf(fmaxf(c, -1.0f), 1.0f);
            a = cc * COS_M - SIN_M * sqrtf(fmaxf(0.0f, 1.0f - cc * cc));  // cos(acos+M)
        } else {
            a = c - MMc;
        }
        alb[b] = a;
    }
}

// --- K1b: pre-normalize ALL weight rows f32 -> bf16 wbn (25.6 MB, L3-resident).
// 4 threads per row, fully coalesced loads and stores. Same numerics as the
// previous per-block normalize (f32 accumulate, bf16 round) -> absmax unchanged.
__global__ __launch_bounds__(256)
void k_wnorm(const float* __restrict__ w, __hip_bfloat16* __restrict__ wbn) {
    int tid = threadIdx.x;
    int r = blockIdx.x * 64 + (tid >> 2);
    int h = tid & 3;                 // quarter-row: 32 floats
    if (r >= CC) return;             // whole 4-lane group uniform
    const float4* src = (const float4*)(w + (size_t)r * DD + h * 32);
    float4 buf[8];
    float ss = 0.f;
    #pragma unroll
    for (int j = 0; j < 8; j++) {
        buf[j] = src[j];
        ss += buf[j].x * buf[j].x + buf[j].y * buf[j].y
            + buf[j].z * buf[j].z + buf[j].w * buf[j].w;
    }
    float tot = ss + __shfl_xor(ss, 1, 64);
    tot += __shfl_xor(tot, 2, 64);   // lanes 4r..4r+3 are wave-adjacent
    float rn = rsqrtf(tot);
    #pragma unroll
    for (int j = 0; j < 4; j++) {
        __hip_bfloat16 tmp[8];
        float4 a = buf[2 * j], b2 = buf[2 * j + 1];
        tmp[0] = __float2bfloat16(a.x * rn);
        tmp[1] = __float2bfloat16(a.y * rn);
        tmp[2] = __float2bfloat16(a.z * rn);
        tmp[3] = __float2bfloat16(a.w * rn);
        tmp[4] = __float2bfloat16(b2.x * rn);
        tmp[5] = __float2bfloat16(b2.y * rn);
        tmp[6] = __float2bfloat16(b2.z * rn);
        tmp[7] = __float2bfloat16(b2.w * rn);
        *(uint4*)(wbn + (size_t)r * DD + h * 32 + j * 8) = *(const uint4*)tmp;
    }
}

// --- K2: ROW-streaming main kernel. Grid (98, 16) = 1568 blocks, 256 thr.
// Block = 32 batch rows x 1024 classes; wave = 32 rows x 256-class strip.
// No LDS, no barriers. Swapped MFMA D[class][batch] = mfma(wbn_frag, exb_frag):
//   col = lane&15 -> batch row bf*16+lrow; row = lquad*4+e -> 4 CONSECUTIVE
//   classes per lane -> direct float4 stores from acc registers.
// Stores advance left-to-right along each out row, 64 B/row/tile at
// consecutive addresses -> L2 write-back merges into full-line streaming
// evictions (hence plain cached stores, NOT nontemporal).
__global__ __launch_bounds__(256, 4)
void k_main(const __hip_bfloat16* __restrict__ exb,
            const __hip_bfloat16* __restrict__ wbn,
            const float* __restrict__ alb,
            const int* __restrict__ labels,
            float* __restrict__ out) {
    int tid = threadIdx.x;
    int wave = tid >> 6, lane = tid & 63;
    int lrow = lane & 15, lquad = lane >> 4;
    int ry = blockIdx.y * ROWS_PB;
    int c0 = blockIdx.x * CLS_PB + wave * CLS_PW;

    // ---- hoist batch fragments (B-operand) + per-row epilogue scalars ----
    short8 bfr[2][4];
    float a2[2];
    int lb2[2];
    #pragma unroll
    for (int bf = 0; bf < 2; bf++) {
        int b = ry + bf * 16 + lrow;
        const short8* brow = (const short8*)(exb + (size_t)b * DD);
        #pragma unroll
        for (int ks = 0; ks < 4; ks++)
            bfr[bf][ks] = brow[ks * 4 + lquad];      // k = ks*32 + lquad*8
        a2[bf] = alb[b];
        lb2[bf] = labels[b];
    }

    // number of whole 16-class tiles for this wave (CC, c0 both multiples of 16)
    int ntiles = 0;
    if (c0 < CC) {
        int rem = (CC - c0) >> 4;
        ntiles = rem < 16 ? rem : 16;
    }
    if (ntiles == 0) return;

    // class-fragment gather base: row (c0+lrow), byte col lquad*16
    const __hip_bfloat16* wp = wbn + (size_t)(c0 + lrow) * DD + lquad * 8;

    short8 cf[4], cfn[4];
    #pragma unroll
    for (int ks = 0; ks < 4; ks++)
        cf[ks] = *(const short8*)(wp + ks * 32);

    for (int t = 0; t < ntiles; t++) {
        // prefetch next tile's class fragments (hide L3 latency under MFMA+epilogue)
        if (t + 1 < ntiles) {
            const __hip_bfloat16* wq = wp + (size_t)(t + 1) * 16 * DD;
            #pragma unroll
            for (int ks = 0; ks < 4; ks++)
                cfn[ks] = *(const short8*)(wq + ks * 32);
        }

        float4v acc[2];
        acc[0] = (float4v)(0.0f);
        acc[1] = (float4v)(0.0f);
        #pragma unroll
        for (int ks = 0; ks < 4; ks++) {
            acc[0] = __builtin_amdgcn_mfma_f32_16x16x32_bf16(cf[ks], bfr[0][ks], acc[0], 0, 0, 0);
            acc[1] = __builtin_amdgcn_mfma_f32_16x16x32_bf16(cf[ks], bfr[1][ks], acc[1], 0, 0, 0);
        }

        // acc[bf][e] = cos(batch ry+bf*16+lrow, class cc+lquad*4+e)
        int cbase = c0 + t * 16 + lquad * 4;
        #pragma unroll
        for (int bf = 0; bf < 2; bf++) {
            float a = a2[bf];
            int lab = lb2[bf];
            int b = ry + bf * 16 + lrow;
            float4v res;
            #pragma unroll
            for (int e = 0; e < 4; e++) {
                float cosv = acc[bf][e];
                float d = cosv - a;
                float rw = ALPHA_F * __expf(-0.5f * d * d);
                res[e] = (cbase + e == lab) ? SCALE_F * a
                                            : SCALE_F * (rw * cosv + rw - 1.0f);
            }
            *(float4v*)(out + (size_t)b * CC + cbase) = res;   // cached: let L2 merge lines
        }

        #pragma unroll
        for (int ks = 0; ks < 4; ks++) cf[ks] = cfn[ks];
    }
}

extern "C" void kernel_launch(void* const* d_in, const int* in_sizes, int n_in,
                              void* d_out, int out_size, void* d_ws, size_t ws_size,
                              hipStream_t stream) {
    const float* feats  = (const float*)d_in[0];
    const int*   labels = (const int*)d_in[1];
    const float* weight = (const float*)d_in[2];
    float* out = (float*)d_out;

    char* ws = (char*)d_ws;
    __hip_bfloat16* exb = (__hip_bfloat16*)ws;                 // 512*128*2   = 131,072 B
    float* alb = (float*)(ws + 131072);                        //               2,048 B
    __hip_bfloat16* wbn = (__hip_bfloat16*)(ws + 133120);      // 100000*128*2 = 25,600,000 B

    hipLaunchKernelGGL(k_prep, dim3(BB), dim3(64), 0, stream,
                       feats, weight, labels, exb, alb);
    hipLaunchKernelGGL(k_wnorm, dim3((CC + 63) / 64), dim3(256), 0, stream,
                       weight, wbn);
    hipLaunchKernelGGL(k_main, dim3(NCHUNK, NROWG), dim3(256), 0, stream,
                       exb, wbn, alb, labels, out);
}

// Round 5
// 255.416 us; speedup vs baseline: 1.4248x; 1.4248x over previous
//
#include <hip/hip_runtime.h>
#include <hip/hip_bf16.h>
#include <math.h>

#define BB 512
#define DD 128
#define CC 100000

#define BLK_M 64
#define BLK_N 64
#define LDA 136                 // bf16 units; 272B row stride -> balanced b128 MFMA reads
#define LDB 136
#define LDT 68                  // f32 units for the transpose view of the A buffer

// XCD-chunked bijective swizzle (m204): nwg=1563, 8 XCDs
#define NWG 1563
#define NXCD 8
#define SWZ_Q (NWG / NXCD)      // 195
#define SWZ_R (NWG % NXCD)      // 3

__device__ __constant__ const float COS_M  =  0.87758256189037271612f;  // cos(0.5)
__device__ __constant__ const float SIN_M  =  0.47942553860420300538f;  // sin(0.5)
__device__ __constant__ const float THRESH = -0.87758256189037271612f;  // cos(pi-0.5)
__device__ __constant__ const float MMc    =  0.23971276930210150269f;  // sin(0.5)*0.5
#define SCALE_F 64.0f
#define ALPHA_F 1.2f

typedef __attribute__((ext_vector_type(8))) short short8;
typedef __attribute__((ext_vector_type(4))) float float4v;

__device__ inline float waveReduceSum(float v) {
    #pragma unroll
    for (int off = 32; off > 0; off >>= 1)
        v += __shfl_xor(v, off, 64);
    return v;
}

// --- K1: fused feats-normalize (-> bf16 exb) + per-row a_lb (full fp32) ---
__global__ void k_prep(const float* __restrict__ feats, const float* __restrict__ w,
                       const int* __restrict__ labels,
                       __hip_bfloat16* __restrict__ exb, float* __restrict__ alb) {
    int b = blockIdx.x;
    int lane = threadIdx.x;          // 64 threads, 2 floats each
    int lab = labels[b];
    float2 f = ((const float2*)(feats + b * DD))[lane];
    float2 g = ((const float2*)(w + (size_t)lab * DD))[lane];
    float nf  = waveReduceSum(f.x * f.x + f.y * f.y);
    float dot = waveReduceSum(f.x * g.x + f.y * g.y);
    float nw  = waveReduceSum(g.x * g.x + g.y * g.y);
    float rn = rsqrtf(nf);
    __hip_bfloat162 o;
    o.x = __float2bfloat16(f.x * rn);
    o.y = __float2bfloat16(f.y * rn);
    ((__hip_bfloat162*)(exb + b * DD))[lane] = o;
    if (lane == 0) {
        float c = dot * rsqrtf(nf * nw);
        float a;
        if (c > THRESH) {
            float cc = fminf(fmaxf(c, -1.0f), 1.0f);
            a = cc * COS_M - SIN_M * sqrtf(fmaxf(0.0f, 1.0f - cc * cc));  // cos(acos+M)
        } else {
            a = c - MMc;
        }
        alb[b] = a;
    }
}

// --- K2: column-tile kernel, 64 cols per block (verified baseline structure) ---
// 1563 blocks, 256 threads (4 waves), 4 blocks/CU (LDS 34,816 B).
// ONE change vs the 254.6us baseline: XCD-chunked blockIdx swizzle so that
// concurrently-resident blocks on one XCD own ADJACENT column tiles ->
// their per-row 256B store segments are contiguous in DRAM (page locality)
// and they share the same exb A-tile in that XCD's L2.
__global__ __launch_bounds__(256, 4)
void k_main(const __hip_bfloat16* __restrict__ exb,
            const float* __restrict__ w,
            const float* __restrict__ alb,
            const int* __restrict__ labels,
            float* __restrict__ out) {
    __shared__ __align__(16) char smemA[BLK_M * LDA * 2];      // 17408 B: bf16 A-tile, then f32 transpose
    __shared__ __align__(16) __hip_bfloat16 Bs[BLK_N][LDB];    // 17408 B

    __hip_bfloat16 (*As)[LDA] = (__hip_bfloat16(*)[LDA])smemA;
    float (*Tr)[LDT] = (float(*)[LDT])smemA;

    int tid = threadIdx.x;

    // ---- bijective XCD-chunked swizzle (HW round-robins orig%8 across XCDs) ----
    int orig = blockIdx.x;
    int xcd = orig & (NXCD - 1);
    int idx = orig >> 3;
    int nb = (xcd < SWZ_R) ? xcd * (SWZ_Q + 1) + idx
                           : SWZ_R * (SWZ_Q + 1) + (xcd - SWZ_R) * SWZ_Q + idx;
    int c0 = nb * BLK_N;

    // ---- normalize BLK_N weight rows into Bs (4 threads per row) ----
    {
        int r = tid >> 2;            // 0..63
        int h = tid & 3;             // quarter-row: 32 floats
        int c = c0 + r;
        float4 buf[8];
        float ss = 0.f;
        if (c < CC) {
            const float4* src = (const float4*)(w + (size_t)c * DD + h * 32);
            #pragma unroll
            for (int j = 0; j < 8; j++) {
                buf[j] = src[j];
                ss += buf[j].x * buf[j].x + buf[j].y * buf[j].y
                    + buf[j].z * buf[j].z + buf[j].w * buf[j].w;
            }
        } else {
            #pragma unroll
            for (int j = 0; j < 8; j++) buf[j] = make_float4(0.f, 0.f, 0.f, 0.f);
        }
        float tot = ss + __shfl_xor(ss, 1, 64);
        tot += __shfl_xor(tot, 2, 64);           // lanes 4r..4r+3 are wave-adjacent
        float rn = (c < CC) ? rsqrtf(tot) : 0.f;
        #pragma unroll
        for (int j = 0; j < 4; j++) {
            __hip_bfloat16 tmp[8];
            float4 a = buf[2 * j], b2 = buf[2 * j + 1];
            tmp[0] = __float2bfloat16(a.x * rn);
            tmp[1] = __float2bfloat16(a.y * rn);
            tmp[2] = __float2bfloat16(a.z * rn);
            tmp[3] = __float2bfloat16(a.w * rn);
            tmp[4] = __float2bfloat16(b2.x * rn);
            tmp[5] = __float2bfloat16(b2.y * rn);
            tmp[6] = __float2bfloat16(b2.z * rn);
            tmp[7] = __float2bfloat16(b2.w * rn);
            *(uint4*)(&Bs[r][h * 32 + j * 8]) = *(const uint4*)tmp;
        }
    }

    int wave = tid >> 6;
    int lane = tid & 63;
    int lrow = lane & 15;
    int lquad = lane >> 4;

    for (int rb = 0; rb < BB / BLK_M; rb++) {
        __syncthreads();   // prev-iter Tr reads done (and normalize done, iter 0)

        // ---- stage A tile (64x128 bf16 = 1024 uint4, 4 per thread) ----
        {
            const uint4* src = (const uint4*)(exb + (size_t)rb * BLK_M * DD);
            #pragma unroll
            for (int j = 0; j < 4; j++) {
                int i = tid + j * 256;
                int r = i >> 4, kc = i & 15;
                *(uint4*)(&As[r][kc * 8]) = src[i];
            }
        }
        __syncthreads();   // A staged, Bs visible

        float4v acc[4];
        #pragma unroll
        for (int i = 0; i < 4; i++) acc[i] = (float4v)(0.0f);

        #pragma unroll
        for (int ks = 0; ks < 4; ks++) {
            int k0 = ks * 32 + lquad * 8;
            short8 bf = *(const short8*)(&Bs[wave * 16 + lrow][k0]);
            #pragma unroll
            for (int mt = 0; mt < 4; mt++) {
                short8 af = *(const short8*)(&As[mt * 16 + lrow][k0]);
                acc[mt] = __builtin_amdgcn_mfma_f32_16x16x32_bf16(af, bf, acc[mt], 0, 0, 0);
            }
        }
        __syncthreads();   // all As reads done; A buffer now reusable as Tr

        // ---- write f32 tile into transpose buffer ----
        // value (mt,reg): row = mt*16 + lquad*4 + reg, col = wave*16 + lrow
        #pragma unroll
        for (int mt = 0; mt < 4; mt++)
            #pragma unroll
            for (int reg = 0; reg < 4; reg++)
                Tr[mt * 16 + lquad * 4 + reg][wave * 16 + lrow] = acc[mt][reg];
        __syncthreads();   // tile transposed

        // ---- row-major epilogue + full-line stores ----
        // out = SCALE*( onehot*a + (1-onehot)*(rw*cos + rw - 1) ), rw = ALPHA*exp(-(cos-a)^2/2)
        #pragma unroll
        for (int it = 0; it < 4; it++) {
            int flat = it * 256 + tid;          // 0..1023
            int r  = flat >> 4;                 // tile row 0..63
            int c4 = flat & 15;                 // float4 index within row
            int b = rb * BLK_M + r;
            int cbase = c0 + c4 * 4;
            if (cbase < CC) {                   // CC%4==0, c0%64==0 -> whole float4 valid
                float a = alb[b];
                int lab = labels[b];
                float4v v = *(const float4v*)(&Tr[r][c4 * 4]);
                float4v res;
                #pragma unroll
                for (int e = 0; e < 4; e++) {
                    float cosv = v[e];
                    float d = cosv - a;
                    float rw = ALPHA_F * __expf(-0.5f * d * d);
                    res[e] = (cbase + e == lab) ? SCALE_F * a
                                                : SCALE_F * (rw * cosv + rw - 1.0f);
                }
                __builtin_nontemporal_store(res, (float4v*)(out + (size_t)b * CC + cbase));
            }
        }
    }
}

extern "C" void kernel_launch(void* const* d_in, const int* in_sizes, int n_in,
                              void* d_out, int out_size, void* d_ws, size_t ws_size,
                              hipStream_t stream) {
    const float* feats  = (const float*)d_in[0];
    const int*   labels = (const int*)d_in[1];
    const float* weight = (const float*)d_in[2];
    float* out = (float*)d_out;

    char* ws = (char*)d_ws;
    __hip_bfloat16* exb = (__hip_bfloat16*)ws;            // 512*128*2 = 131072 B
    float* alb = (float*)(ws + 131072);                   // 2048 B

    hipLaunchKernelGGL(k_prep, dim3(BB), dim3(64), 0, stream,
                       feats, weight, labels, exb, alb);

    dim3 grid((CC + BLK_N - 1) / BLK_N);                  // 1563 column tiles
    hipLaunchKernelGGL(k_main, grid, dim3(256), 0, stream,
                       exb, weight, alb, labels, out);
}